// Round 1
// baseline (196.210 us; speedup 1.0000x reference)
//
#include <hip/hip_runtime.h>
#include <stdint.h>

#define B_ 16
#define S_ 128
#define H_ 768
#define K_ 4
#define L_ 2
#define T_ (B_*S_)   // 2048

typedef __attribute__((ext_vector_type(4))) float f32x4;
typedef __attribute__((ext_vector_type(8))) short s16x8;
typedef __bf16 bf16x8 __attribute__((ext_vector_type(8)));
typedef unsigned short u16;

// ---------- bf16 helpers ----------
__device__ inline u16 f2bf(float f) {
    union { float f; uint32_t u; } v; v.f = f;
    uint32_t u = v.u;
    return (u16)((u + 0x7fffu + ((u >> 16) & 1u)) >> 16);
}

__device__ inline ushort4 f2bf4(float4 v) {
    ushort4 r; r.x = f2bf(v.x); r.y = f2bf(v.y); r.z = f2bf(v.z); r.w = f2bf(v.w);
    return r;
}

// ---------- MFMA wrapper: tolerant to either builtin signature (short8 / bf16x8) ----------
template <typename T>
__device__ inline auto mfma_impl(T a, T b, f32x4 c, int)
    -> decltype(__builtin_amdgcn_mfma_f32_16x16x32_bf16(a, b, c, 0, 0, 0)) {
    return __builtin_amdgcn_mfma_f32_16x16x32_bf16(a, b, c, 0, 0, 0);
}
template <typename T>
__device__ inline f32x4 mfma_impl(T a, T b, f32x4 c, long) {
    return __builtin_amdgcn_mfma_f32_16x16x32_bf16(
        __builtin_bit_cast(bf16x8, a), __builtin_bit_cast(bf16x8, b), c, 0, 0, 0);
}
__device__ inline f32x4 mfma16(s16x8 a, s16x8 b, f32x4 c) {
    return mfma_impl(a, b, c, 0);
}

// ---------- async global->LDS, 16B/lane ----------
__device__ inline void gload_lds16(const void* g, void* l) {
    __builtin_amdgcn_global_load_lds(
        (__attribute__((address_space(1))) void*)(g),
        (__attribute__((address_space(3))) void*)(l), 16, 0, 0);
}

// Stage a 128-row x 128-byte (64 bf16) tile into 16 KiB of LDS.
// Linear LDS dest (required by global_load_lds) + inverse-XOR-swizzled global
// source; reads must apply the same swizzle (involution): byte ^= (row&7)<<4.
__device__ inline void stage_tile(const char* gbase, int rowStrideBytes, u16* lds, int tid) {
    const int lane = tid & 63;
    const int w = tid >> 6;           // wave id (0..3)
    const int lr = lane >> 3;         // row within 8-row segment
    const int cb = (lane & 7) << 4;   // byte col within 128-byte row
    #pragma unroll
    for (int j = 0; j < 4; ++j) {
        const int seg = j * 4 + w;          // 0..15, wave-uniform
        const int row = seg * 8 + lr;       // 0..127
        const int sb = cb ^ ((row & 7) << 4);
        gload_lds16(gbase + (size_t)row * rowStrideBytes + sb,
                    lds + seg * 512);       // 512 u16 = 1024 B per wave-issue
    }
}

// Swizzled ds_read_b128 of an MFMA fragment (8 bf16 along K at one row).
__device__ inline s16x8 read_frag(const u16* lds, int row, int colByte) {
    const int bir = colByte ^ ((row & 7) << 4);
    return *(const s16x8*)((const char*)lds + row * 128 + bir);
}

// ---------- prep kernels ----------
__global__ void prep_weights(const float* __restrict__ Wg_in, const float* __restrict__ Wg_out,
                             const float* __restrict__ W_in,  const float* __restrict__ W_out,
                             const float* __restrict__ W_loop, const float* __restrict__ sent,
                             u16* __restrict__ Wg_all, u16* __restrict__ W_all,
                             u16* __restrict__ Wl, u16* __restrict__ X0) {
    const int i4 = blockIdx.x * blockDim.x + threadIdx.x;   // float4 index
    const int NW4 = L_ * K_ * H_ * H_ / 4;                  // 1,179,648
    const int KHH4 = K_ * H_ * H_ / 4;                      // 589,824
    if (i4 < NW4) {
        const int l = i4 / KHH4;
        const int rem = i4 - l * KHH4;
        const int d0 = (l * 2) * KHH4 + rem;
        const int d1 = d0 + KHH4;
        ((ushort4*)Wg_all)[d0] = f2bf4(((const float4*)Wg_in)[i4]);
        ((ushort4*)Wg_all)[d1] = f2bf4(((const float4*)Wg_out)[i4]);
        ((ushort4*)W_all)[d0]  = f2bf4(((const float4*)W_in)[i4]);
        ((ushort4*)W_all)[d1]  = f2bf4(((const float4*)W_out)[i4]);
    }
    if (i4 < L_ * H_ * H_ / 4)  ((ushort4*)Wl)[i4] = f2bf4(((const float4*)W_loop)[i4]);
    if (i4 < T_ * H_ / 4)       ((ushort4*)X0)[i4] = f2bf4(((const float4*)sent)[i4]);
}

// adjA[p][b][t][s]: p=dir*4+k; dir 0 (in): adj[b,k,s,t] (transposed), dir 1 (out): adj[b,k,t,s]
__global__ void prep_adj(const float* __restrict__ adj, u16* __restrict__ adjA) {
    const int idx = blockIdx.x * blockDim.x + threadIdx.x;   // 0 .. 2^21-1
    const int s = idx & 127;
    const int t = (idx >> 7) & 127;
    const int b = (idx >> 14) & 15;
    const int p = idx >> 18;
    const int dir = p >> 2, k = p & 3;
    const float v = dir ? adj[(((size_t)b * K_ + k) * S_ + t) * S_ + s]
                        : adj[(((size_t)b * K_ + k) * S_ + s) * S_ + t];
    adjA[idx] = f2bf(v);
}

// ---------- GEMM 1: gated weight GEMMs + self loop ----------
// grid (6 n-tiles, 16 m-tiles(=batches), 9 problems), block 256 (4 waves, 2x2)
__global__ __launch_bounds__(256, 2)
void gemm1_kernel(const u16* __restrict__ Xb,
                  const u16* __restrict__ Wg_all, const u16* __restrict__ W_all,
                  const u16* __restrict__ Wl,
                  const float* __restrict__ bg_in, const float* __restrict__ bg_out,
                  const float* __restrict__ b_in,  const float* __restrict__ b_out,
                  int layer,
                  u16* __restrict__ Rel2, float* __restrict__ SBuf) {
    __shared__ u16 lA[128 * 64];
    __shared__ u16 lBr[128 * 64];
    __shared__ u16 lBg[128 * 64];

    const int tid = threadIdx.x;
    const int lane = tid & 63;
    const int w = tid >> 6;
    const int wm = w >> 1, wn = w & 1;
    const int p = blockIdx.z;
    const bool gated = (p < 8);
    const int m0 = blockIdx.y * 128;   // token tile == batch blockIdx.y
    const int n0 = blockIdx.x * 128;   // h-out tile

    const u16* Wr;
    const u16* Wg = nullptr;
    if (gated) {
        const int dir = p >> 2, k = p & 3;
        const size_t woff = ((size_t)(layer * 2 + dir) * K_ + k) * (size_t)(H_ * H_);
        Wg = Wg_all + woff;
        Wr = W_all + woff;
    } else {
        Wr = Wl + (size_t)layer * H_ * H_;
    }

    const f32x4 zf = {0.f, 0.f, 0.f, 0.f};
    f32x4 accr[4][4], accg[4][4];
    #pragma unroll
    for (int i = 0; i < 4; ++i)
        #pragma unroll
        for (int j = 0; j < 4; ++j) { accr[i][j] = zf; accg[i][j] = zf; }

    const char* Abase = (const char*)Xb + (size_t)m0 * (H_ * 2);
    const char* Rbase = (const char*)Wr + (size_t)n0 * (H_ * 2);
    const char* Gbase = gated ? ((const char*)Wg + (size_t)n0 * (H_ * 2)) : nullptr;

    for (int kt = 0; kt < H_ / 64; ++kt) {
        __syncthreads();
        stage_tile(Abase + kt * 128, H_ * 2, lA, tid);
        stage_tile(Rbase + kt * 128, H_ * 2, lBr, tid);
        if (gated) stage_tile(Gbase + kt * 128, H_ * 2, lBg, tid);
        __syncthreads();
        #pragma unroll
        for (int kq = 0; kq < 2; ++kq) {
            const int cb = kq * 64 + ((lane >> 4) << 4);
            s16x8 a[4], br[4], bg[4];
            #pragma unroll
            for (int i = 0; i < 4; ++i)
                a[i] = read_frag(lA, wm * 64 + i * 16 + (lane & 15), cb);
            #pragma unroll
            for (int j = 0; j < 4; ++j)
                br[j] = read_frag(lBr, wn * 64 + j * 16 + (lane & 15), cb);
            if (gated) {
                #pragma unroll
                for (int j = 0; j < 4; ++j)
                    bg[j] = read_frag(lBg, wn * 64 + j * 16 + (lane & 15), cb);
            }
            #pragma unroll
            for (int i = 0; i < 4; ++i) {
                #pragma unroll
                for (int j = 0; j < 4; ++j) {
                    accr[i][j] = mfma16(a[i], br[j], accr[i][j]);
                    if (gated) accg[i][j] = mfma16(a[i], bg[j], accg[i][j]);
                }
            }
        }
    }

    if (gated) {
        const int dir = p >> 2, k = p & 3;
        const float* bgp = (dir ? bg_out : bg_in) + ((size_t)layer * K_ + k) * H_;
        const float* brp = (dir ? b_out  : b_in ) + ((size_t)layer * K_ + k) * H_;
        const int b = blockIdx.y;
        #pragma unroll
        for (int j = 0; j < 4; ++j) {
            const int h = n0 + wn * 64 + j * 16 + (lane & 15);
            const float bgv = bgp[h];
            const float brv = brp[h];
            u16* dst = Rel2 + (((size_t)p * B_ + b) * H_ + h) * S_;
            #pragma unroll
            for (int i = 0; i < 4; ++i) {
                const int s0 = wm * 64 + i * 16 + ((lane >> 4) << 2);
                u16 tmp[4];
                #pragma unroll
                for (int r = 0; r < 4; ++r) {
                    const float g = accg[i][j][r] + bgv;
                    const float v = accr[i][j][r] + brv;
                    const float rel = 0.5f * v / (1.f + __expf(-g));
                    tmp[r] = f2bf(rel);
                }
                ushort4 pk; pk.x = tmp[0]; pk.y = tmp[1]; pk.z = tmp[2]; pk.w = tmp[3];
                *(ushort4*)(dst + s0) = pk;
            }
        }
    } else {
        #pragma unroll
        for (int i = 0; i < 4; ++i) {
            const int t0 = m0 + wm * 64 + i * 16 + ((lane >> 4) << 2);
            #pragma unroll
            for (int j = 0; j < 4; ++j) {
                const int h = n0 + wn * 64 + j * 16 + (lane & 15);
                #pragma unroll
                for (int r = 0; r < 4; ++r)
                    SBuf[(size_t)(t0 + r) * H_ + h] = accr[i][j][r];
            }
        }
    }
}

// ---------- GEMM 2: adjacency contraction + loop term + ReLU ----------
// grid (6 h-tiles, 16 batches), block 256 (4 waves, 2x2)
__global__ __launch_bounds__(256, 2)
void gemm2_kernel(const u16* __restrict__ adjA, const u16* __restrict__ Rel2,
                  const float* __restrict__ SBuf,
                  u16* __restrict__ Xn, float* __restrict__ Out, int lastLayer) {
    __shared__ u16 lA[128 * 64];
    __shared__ u16 lB[128 * 64];

    const int tid = threadIdx.x;
    const int lane = tid & 63;
    const int w = tid >> 6;
    const int wm = w >> 1, wn = w & 1;
    const int h0 = blockIdx.x * 128;
    const int b = blockIdx.y;

    const f32x4 zf = {0.f, 0.f, 0.f, 0.f};
    f32x4 acc[4][4];
    #pragma unroll
    for (int i = 0; i < 4; ++i)
        #pragma unroll
        for (int j = 0; j < 4; ++j) acc[i][j] = zf;

    for (int p = 0; p < 8; ++p) {
        const char* Ab = (const char*)adjA + ((size_t)p * B_ + b) * (S_ * S_ * 2);
        const char* Bb = (const char*)Rel2 + (((size_t)p * B_ + b) * H_ + h0) * (S_ * 2);
        #pragma unroll
        for (int sc = 0; sc < 2; ++sc) {
            __syncthreads();
            stage_tile(Ab + sc * 128, S_ * 2, lA, tid);
            stage_tile(Bb + sc * 128, S_ * 2, lB, tid);
            __syncthreads();
            #pragma unroll
            for (int kq = 0; kq < 2; ++kq) {
                const int cb = kq * 64 + ((lane >> 4) << 4);
                s16x8 a[4], bb[4];
                #pragma unroll
                for (int i = 0; i < 4; ++i)
                    a[i] = read_frag(lA, wm * 64 + i * 16 + (lane & 15), cb);
                #pragma unroll
                for (int j = 0; j < 4; ++j)
                    bb[j] = read_frag(lB, wn * 64 + j * 16 + (lane & 15), cb);
                #pragma unroll
                for (int i = 0; i < 4; ++i)
                    #pragma unroll
                    for (int j = 0; j < 4; ++j)
                        acc[i][j] = mfma16(a[i], bb[j], acc[i][j]);
            }
        }
    }

    #pragma unroll
    for (int i = 0; i < 4; ++i) {
        const int tl = wm * 64 + i * 16 + ((lane >> 4) << 2);
        #pragma unroll
        for (int j = 0; j < 4; ++j) {
            const int h = h0 + wn * 64 + j * 16 + (lane & 15);
            #pragma unroll
            for (int r = 0; r < 4; ++r) {
                const size_t t = (size_t)b * S_ + tl + r;
                float v = acc[i][j][r] + SBuf[t * H_ + h];
                v = fmaxf(v, 0.f);
                if (lastLayer) Out[t * H_ + h] = v;
                else           Xn[t * H_ + h] = f2bf(v);
            }
        }
    }
}

// ---------- launch ----------
extern "C" void kernel_launch(void* const* d_in, const int* in_sizes, int n_in,
                              void* d_out, int out_size, void* d_ws, size_t ws_size,
                              hipStream_t stream) {
    const float* sent   = (const float*)d_in[0];
    const float* adj    = (const float*)d_in[1];
    const float* W_in   = (const float*)d_in[2];
    const float* b_in   = (const float*)d_in[3];
    const float* W_out  = (const float*)d_in[4];
    const float* b_out  = (const float*)d_in[5];
    const float* Wg_in  = (const float*)d_in[6];
    const float* bg_in  = (const float*)d_in[7];
    const float* Wg_out = (const float*)d_in[8];
    const float* bg_out = (const float*)d_in[9];
    const float* W_loop = (const float*)d_in[10];

    char* ws = (char*)d_ws;
    u16* Wg_all = (u16*)(ws);                  // L*2*K*H*H*2   = 18,874,368 B
    u16* W_all  = (u16*)(ws + 18874368);       // 18,874,368 B
    u16* Wl     = (u16*)(ws + 37748736);       // L*H*H*2       =  2,359,296 B
    u16* adjA   = (u16*)(ws + 40108032);       // 8*B*S*S*2     =  4,194,304 B
    u16* X0     = (u16*)(ws + 44302336);       // T*H*2         =  3,145,728 B
    u16* X1     = (u16*)(ws + 47448064);       //                  3,145,728 B
    u16* Rel2   = (u16*)(ws + 50593792);       // 8*B*H*S*2     = 25,165,824 B
    float* SBuf = (float*)(ws + 75759616);     // T*H*4         =  6,291,456 B  (end 82,051,072)

    prep_weights<<<4608, 256, 0, stream>>>(Wg_in, Wg_out, W_in, W_out, W_loop, sent,
                                           Wg_all, W_all, Wl, X0);
    prep_adj<<<8192, 256, 0, stream>>>(adj, adjA);

    u16* Xc = X0;
    u16* Xn = X1;
    for (int l = 0; l < L_; ++l) {
        gemm1_kernel<<<dim3(6, 16, 9), 256, 0, stream>>>(Xc, Wg_all, W_all, Wl,
                                                         bg_in, bg_out, b_in, b_out,
                                                         l, Rel2, SBuf);
        gemm2_kernel<<<dim3(6, 16), 256, 0, stream>>>(adjA, Rel2, SBuf, Xn,
                                                      (float*)d_out, l == L_ - 1);
        u16* t = Xc; Xc = Xn; Xn = t;
    }
}